// Round 21
// baseline (53.488 us; speedup 1.0000x reference)
//
#include <hip/hip_runtime.h>
#include <hip/hip_bf16.h>
#include <hip/hip_fp16.h>

#define NH 4
#define HD 32
#define PAD 3
#define HW 56
#define NPIX (8*HW*HW)          // 25088 pixels
#define SCALE 0.17677669529663687f

// ---------------- workspace layout (bytes) ----------------
// qs    : fp16 [8][4][56][56][32]    6,422,528  (q, pre-scaled)
// kbuf  : fp16 [8][4][56][56][32]    6,422,528
// vbuf  : fp16 [8][4][56][56][32]    6,422,528
// xh    : fp16 [25088][128]          6,422,528  (attn from natt)
// W fp16: wqh 98,304; wph 32,768
#define QS_OFF   0
#define K_OFF    12845056
#define V_OFF    (K_OFF + 6422528)
#define XH_OFF   (V_OFF + 6422528)      // attn (written by natt)
#define XL_OFF   (XH_OFF + 6422528)     // (unused)
#define WQH_OFF  (XL_OFF + 6422528)
#define WPH_OFF  (WQH_OFF + 98304)

typedef __attribute__((ext_vector_type(8))) short short8v;
typedef __attribute__((ext_vector_type(4))) float f32x4;

__device__ __forceinline__ unsigned short f2h(float x) {       // f32 -> fp16 bits, RNE
    return __half_as_ushort(__float2half_rn(x));
}

// packed-fp16 8-dot with f32 finish: 2 chains of {mul2, fma2} + hadd2 + 2 cvt
__device__ __forceinline__ float dot8h(const __half2* q2, uint4 k) {
    __half2 k0 = *(__half2*)&k.x, k1 = *(__half2*)&k.y;
    __half2 k2 = *(__half2*)&k.z, k3 = *(__half2*)&k.w;
    __half2 a = __hmul2(q2[0], k0);
    a = __hfma2(q2[1], k1, a);
    __half2 b = __hmul2(q2[2], k2);
    b = __hfma2(q2[3], k3, b);
    __half2 s2 = __hadd2(a, b);
    return __low2float(s2) + __high2float(s2);
}

// quad (4-lane) sum via DPP quad_perm: xor1 = 0xB1, xor2 = 0x4E. VALU-only.
__device__ __forceinline__ float quad_sum(float x) {
    x += __int_as_float(__builtin_amdgcn_update_dpp(0, __float_as_int(x), 0xB1, 0xF, 0xF, true));
    x += __int_as_float(__builtin_amdgcn_update_dpp(0, __float_as_int(x), 0x4E, 0xF, 0xF, true));
    return x;
}

// ---------------------------------------------------------------------------
// Weight convert (f32 -> fp16): W_qkv 12288 f4 + W_proj 4096 f4.
// ---------------------------------------------------------------------------
__global__ __launch_bounds__(256) void split_k(
    const float* __restrict__ wq, const float* __restrict__ wp,
    unsigned short* __restrict__ wqh, unsigned short* __restrict__ wph)
{
    int idx = blockIdx.x * 256 + threadIdx.x;
    if (idx >= 16384) return;
    const float* src; unsigned short* dh; int off;
    if (idx < 12288) { src = wq; dh = wqh; off = idx; }
    else             { src = wp; dh = wph; off = idx - 12288; }
    float4 v = ((const float4*)src)[off];
    ushort4 h;
    h.x = f2h(v.x); h.y = f2h(v.y); h.z = f2h(v.z); h.w = f2h(v.w);
    ((ushort4*)dh)[off] = h;
}

// ---------------------------------------------------------------------------
// Fused-N MFMA GEMM, plain fp16 (round-20 version, unchanged).
// grid = 392 m-blocks; A-tile staged once; NPH n-phases restage 16 KB B.
//  SELQKV=1: NPH=6, A = f32 x -> fp16 in-kernel; q/k/v scatter epilogue.
//  SELQKV=0: NPH=2, A = attn fp16; f32-row epilogue.
// LDS 32 KB.  XOR swizzle byte ^= (row&7)<<4 -> conflict-free b128 reads.
// ---------------------------------------------------------------------------
template <int SELQKV>
__global__ __launch_bounds__(256, 2) void gemm_fused(
    const float* __restrict__ Af32,
    const unsigned short* __restrict__ Axh,
    const unsigned short* __restrict__ Bgh,
    const float* __restrict__ bias,
    unsigned short* __restrict__ outq, unsigned short* __restrict__ outk,
    unsigned short* __restrict__ outv, float* __restrict__ outp)
{
    __shared__ unsigned short sAh[64 * 128];
    __shared__ unsigned short sBh[64 * 128];

    const int tid = threadIdx.x;
    const int m0 = blockIdx.x * 64;
    constexpr int NPH = SELQKV ? 6 : 2;

    // ---- stage A once (fp16) ----
    if constexpr (SELQKV) {
#pragma unroll
        for (int it = 0; it < 8; ++it) {
            int idx = tid + it * 256;          // 0..2047 float4 chunks
            int row = idx >> 5;                // 0..63
            int c4  = idx & 31;
            float4 a = *(const float4*)(Af32 + (size_t)(m0 + row) * 128 + c4 * 4);
            int byte = (row * 256 + c4 * 8) ^ ((row & 7) << 4);
            ushort4 h;
            h.x = f2h(a.x); h.y = f2h(a.y); h.z = f2h(a.z); h.w = f2h(a.w);
            *(ushort4*)((char*)sAh + byte) = h;
        }
    } else {
#pragma unroll
        for (int it = 0; it < 4; ++it) {
            int chunk = it * 256 + tid;        // 0..1023
            int row = chunk >> 4, c16 = chunk & 15;
            int byte = (row * 256 + c16 * 16) ^ ((row & 7) << 4);
            size_t ga = (size_t)(m0 + row) * 128 + c16 * 8;
            *(uint4*)((char*)sAh + byte) = *(const uint4*)(Axh + ga);
        }
    }

    const int lane = tid & 63;
    const int w  = tid >> 6;
    const int wr = w >> 1, wc = w & 1;       // 2x2 waves -> 64x64
    const int fr  = lane & 15;
    const int kqb = (lane >> 4) * 16;        // k byte offset within 64B group
    const int cl = lane & 15;
    const int rq = lane >> 4;

    for (int ph = 0; ph < NPH; ++ph) {
        const int n0 = ph * 64;
        if (ph > 0) __syncthreads();         // prior mfma reads done before B overwrite
#pragma unroll
        for (int it = 0; it < 4; ++it) {
            int chunk = it * 256 + tid;      // 0..1023
            int row = chunk >> 4, c16 = chunk & 15;
            int byte = (row * 256 + c16 * 16) ^ ((row & 7) << 4);
            size_t gb = (size_t)(n0 + row) * 128 + c16 * 8;
            *(uint4*)((char*)sBh + byte) = *(const uint4*)(Bgh + gb);
        }
        __syncthreads();

        f32x4 acc[2][2];
#pragma unroll
        for (int i = 0; i < 2; ++i)
#pragma unroll
            for (int j = 0; j < 2; ++j) acc[i][j] = (f32x4){0.f, 0.f, 0.f, 0.f};

#pragma unroll
        for (int ks = 0; ks < 4; ++ks) {
            short8v ah[2], bh[2];
#pragma unroll
            for (int mi = 0; mi < 2; ++mi) {
                int row = wr * 32 + mi * 16 + fr;
                int byte = (row * 256 + ks * 64 + kqb) ^ ((row & 7) << 4);
                ah[mi] = *(const short8v*)((const char*)sAh + byte);
            }
#pragma unroll
            for (int ni = 0; ni < 2; ++ni) {
                int row = wc * 32 + ni * 16 + fr;
                int byte = (row * 256 + ks * 64 + kqb) ^ ((row & 7) << 4);
                bh[ni] = *(const short8v*)((const char*)sBh + byte);
            }
#pragma unroll
            for (int mi = 0; mi < 2; ++mi)
#pragma unroll
                for (int ni = 0; ni < 2; ++ni)
                    acc[mi][ni] = __builtin_amdgcn_mfma_f32_16x16x32_f16(ah[mi], bh[ni], acc[mi][ni], 0, 0, 0);
        }

        // ---- epilogue: C/D layout col=lane&15, row=4*(lane>>4)+reg ----
#pragma unroll
        for (int mi = 0; mi < 2; ++mi) {
#pragma unroll
            for (int reg = 0; reg < 4; ++reg) {
                int m = m0 + wr * 32 + mi * 16 + rq * 4 + reg;
                if constexpr (SELQKV) {
                    int b = m / 3136;
                    int r = m - b * 3136;
                    int y = r / 56;
                    int x = r - y * 56;
#pragma unroll
                    for (int ni = 0; ni < 2; ++ni) {
                        int nn = n0 + wc * 32 + ni * 16 + cl;   // 0..383
                        float val = acc[mi][ni][reg] + bias[nn];
                        int sel = nn >> 7;                      // 0=q 1=k 2=v
                        int nl = nn & 127;
                        int h = nl >> 5, d = nl & 31;
                        size_t oi = ((size_t)((b * NH + h) * 3136) + y * 56 + x) * 32 + d;
                        if (sel == 0)      outq[oi] = f2h(val * SCALE);   // q fp16
                        else if (sel == 1) outk[oi] = f2h(val);
                        else               outv[oi] = f2h(val);
                    }
                } else {
#pragma unroll
                    for (int ni = 0; ni < 2; ++ni) {
                        int nn = n0 + wc * 32 + ni * 16 + cl;
                        outp[(size_t)m * 128 + nn] = acc[mi][ni][reg] + bias[nn];
                    }
                }
            }
        }
    }
}

// ---------------------------------------------------------------------------
// Neighborhood attention v9: v8 with V kept fp16 in LDS ([pix][c] uint4,
// same as K).  LDS 25.1 KB -> 6 blocks/CU = 24 waves/CU (was 4 blocks/16
// waves with f32 V) — +50% TLP for a latency-bound kernel; LDS read bytes
// per key-thread 48 -> 32 (-33%).  axpy unpacks V with 4x half2->float2
// (acc stays f32; V quantization already in storage).  Staging is now a
// straight uint4 copy for both K and V.
// ---------------------------------------------------------------------------
__global__ __launch_bounds__(256) void natt_k(
    const unsigned short* __restrict__ qs, const unsigned short* __restrict__ kb,
    const unsigned short* __restrict__ vb, const float* __restrict__ rpb,
    unsigned short* __restrict__ attn_h)
{
    __shared__ uint4 ks[196 * 4];   // K fp16 [pix][c], 12544 B
    __shared__ uint4 vs[196 * 4];   // V fp16 [pix][c], 12544 B

    const int tid = threadIdx.x;
    const int b = blockIdx.z, h = blockIdx.y;
    const int tyy = blockIdx.x / 7, txx = blockIdx.x - tyy * 7;  // 7x7 tiles
    const int y0 = tyy * 8, x0 = txx * 8;
    const int bh = b * NH + h;

    const int p = tid >> 2, c = tid & 3;   // quads 4-aligned -> DPP partners co-active
    const int py = p >> 3;
    const int pxx = p & 7;

    // hoisted q load (fp16, 16B) — stays packed in 4 half2 regs
    __half2 q2[4];
    {
        uint4 qv = *(const uint4*)(qs +
            ((size_t)(bh * 3136) + (y0 + py) * 56 + (x0 + pxx)) * 32 + c * 8);
        q2[0] = *(__half2*)&qv.x; q2[1] = *(__half2*)&qv.y;
        q2[2] = *(__half2*)&qv.z; q2[3] = *(__half2*)&qv.w;
    }

    const uint4* kg = (const uint4*)kb;  // 4 uint4 per pixel (32 fp16)
    const uint4* vg = (const uint4*)vb;
    for (int idx = tid; idx < 784; idx += 256) {   // 196 pix * 4 chunks
        int pix = idx >> 2, cc = idx & 3;
        int i = pix / 14;
        int j = pix - i * 14;
        int y = y0 + i - PAD;
        int x = x0 + j - PAD;
        uint4 zk = make_uint4(0u, 0u, 0u, 0u);
        uint4 zv = make_uint4(0u, 0u, 0u, 0u);
        if ((unsigned)y < 56u && (unsigned)x < 56u) {
            int g = ((bh * 3136) + y * 56 + x) * 4 + cc;
            zk = kg[g];
            zv = vg[g];
        }
        ks[idx] = zk;
        vs[idx] = zv;
    }
    __syncthreads();

    float acc[8];
#pragma unroll
    for (int d = 0; d < 8; ++d) acc[d] = 0.f;
    float l = 0.f;

    const float* rph = rpb + h * 49;       // uniform index -> scalar loads

#pragma unroll
    for (int dy = 0; dy < 7; ++dy) {
        int rowpix = (py + dy) * 14 + pxx;
#pragma unroll
        for (int dx = 0; dx < 7; ++dx) {
            int pix = rowpix + dx;
            float s  = dot8h(q2, ks[pix * 4 + c]);
            float sf = quad_sum(s) + rph[dy * 7 + dx];
            float e  = __expf(sf);
            l += e;
            uint4 vvk = vs[pix * 4 + c];
            float2 f0 = __half22float2(*(__half2*)&vvk.x);
            float2 f1 = __half22float2(*(__half2*)&vvk.y);
            float2 f2 = __half22float2(*(__half2*)&vvk.z);
            float2 f3 = __half22float2(*(__half2*)&vvk.w);
            acc[0] = fmaf(e, f0.x, acc[0]); acc[1] = fmaf(e, f0.y, acc[1]);
            acc[2] = fmaf(e, f1.x, acc[2]); acc[3] = fmaf(e, f1.y, acc[3]);
            acc[4] = fmaf(e, f2.x, acc[4]); acc[5] = fmaf(e, f2.y, acc[5]);
            acc[6] = fmaf(e, f3.x, acc[6]); acc[7] = fmaf(e, f3.y, acc[7]);
        }
    }

    float rl = 1.0f / l;

    // pack 8 dims -> fp16 uint4, single b128 store
    unsigned short hv[8];
#pragma unroll
    for (int d = 0; d < 8; ++d) hv[d] = f2h(acc[d] * rl);
    uint4 uh;
    uh.x = (unsigned)hv[0] | ((unsigned)hv[1] << 16);
    uh.y = (unsigned)hv[2] | ((unsigned)hv[3] << 16);
    uh.z = (unsigned)hv[4] | ((unsigned)hv[5] << 16);
    uh.w = (unsigned)hv[6] | ((unsigned)hv[7] << 16);

    size_t base = ((size_t)(b * 3136) + (y0 + py) * 56 + (x0 + pxx)) * 128 + h * 32 + c * 8;
    *(uint4*)(attn_h + base) = uh;
}

extern "C" void kernel_launch(void* const* d_in, const int* in_sizes, int n_in,
                              void* d_out, int out_size, void* d_ws, size_t ws_size,
                              hipStream_t stream)
{
    const float* x     = (const float*)d_in[0];
    const float* Wqkv  = (const float*)d_in[1];
    const float* bqkv  = (const float*)d_in[2];
    const float* rpb   = (const float*)d_in[3];
    const float* Wproj = (const float*)d_in[4];
    const float* bproj = (const float*)d_in[5];
    float* out = (float*)d_out;

    char* ws = (char*)d_ws;
    unsigned short* qsb  = (unsigned short*)(ws + QS_OFF);   // q fp16 (pre-scaled)
    unsigned short* kbuf = (unsigned short*)(ws + K_OFF);
    unsigned short* vbuf = (unsigned short*)(ws + V_OFF);
    unsigned short* xh   = (unsigned short*)(ws + XH_OFF);   // attn fp16 (from natt)
    unsigned short* wqh  = (unsigned short*)(ws + WQH_OFF);
    unsigned short* wph  = (unsigned short*)(ws + WPH_OFF);

    // 0) convert weights to fp16 (tiny)
    split_k<<<64, 256, 0, stream>>>(Wqkv, Wproj, wqh, wph);

    // 1) QKV projection: 392 m-blocks, 6 internal n-phases (A staged once,
    //    plain fp16 -> 1 MFMA/frag, 32 KB LDS)
    gemm_fused<1><<<392, 256, 0, stream>>>(x, nullptr, wqh, bqkv,
                                           qsb, kbuf, vbuf, nullptr);

    // 2) neighborhood attention (v9, fp16 V in LDS): 49 x 4 x 8, 256 thr
    natt_k<<<dim3(49, NH, 8), 256, 0, stream>>>(qsb, kbuf, vbuf, rpb, xh);

    // 3) output projection: 392 m-blocks, 2 internal n-phases, plain fp16
    gemm_fused<0><<<392, 256, 0, stream>>>(nullptr, xh, wph, bproj,
                                           nullptr, nullptr, nullptr, out);
}

// Round 22
// 52.285 us; speedup vs baseline: 1.0230x; 1.0230x over previous
//
#include <hip/hip_runtime.h>
#include <hip/hip_bf16.h>
#include <hip/hip_fp16.h>

#define NH 4
#define HD 32
#define PAD 3
#define HW 56
#define NPIX (8*HW*HW)          // 25088 pixels
#define SCALE 0.17677669529663687f

// ---------------- workspace layout (bytes) ----------------
// qs    : fp16 [8][4][56][56][32]    6,422,528  (q, pre-scaled)
// kbuf  : fp16 [8][4][56][56][32]    6,422,528
// vbuf  : fp16 [8][4][56][56][32]    6,422,528
// xh    : fp16 [25088][128]          6,422,528  (attn from natt)
// W fp16: wqh 98,304; wph 32,768
#define QS_OFF   0
#define K_OFF    12845056
#define V_OFF    (K_OFF + 6422528)
#define XH_OFF   (V_OFF + 6422528)      // attn (written by natt)
#define XL_OFF   (XH_OFF + 6422528)     // (unused)
#define WQH_OFF  (XL_OFF + 6422528)
#define WPH_OFF  (WQH_OFF + 98304)

typedef __attribute__((ext_vector_type(8))) short short8v;
typedef __attribute__((ext_vector_type(4))) float f32x4;

__device__ __forceinline__ unsigned short f2h(float x) {       // f32 -> fp16 bits, RNE
    return __half_as_ushort(__float2half_rn(x));
}

// packed-fp16 8-dot with f32 finish: 2 chains of {mul2, fma2} + hadd2 + 2 cvt
__device__ __forceinline__ float dot8h(const __half2* q2, uint4 k) {
    __half2 k0 = *(__half2*)&k.x, k1 = *(__half2*)&k.y;
    __half2 k2 = *(__half2*)&k.z, k3 = *(__half2*)&k.w;
    __half2 a = __hmul2(q2[0], k0);
    a = __hfma2(q2[1], k1, a);
    __half2 b = __hmul2(q2[2], k2);
    b = __hfma2(q2[3], k3, b);
    __half2 s2 = __hadd2(a, b);
    return __low2float(s2) + __high2float(s2);
}

// quad (4-lane) sum via DPP quad_perm: xor1 = 0xB1, xor2 = 0x4E. VALU-only.
__device__ __forceinline__ float quad_sum(float x) {
    x += __int_as_float(__builtin_amdgcn_update_dpp(0, __float_as_int(x), 0xB1, 0xF, 0xF, true));
    x += __int_as_float(__builtin_amdgcn_update_dpp(0, __float_as_int(x), 0x4E, 0xF, 0xF, true));
    return x;
}

// ---------------------------------------------------------------------------
// Weight convert (f32 -> fp16): W_qkv 12288 f4 + W_proj 4096 f4.
// ---------------------------------------------------------------------------
__global__ __launch_bounds__(256) void split_k(
    const float* __restrict__ wq, const float* __restrict__ wp,
    unsigned short* __restrict__ wqh, unsigned short* __restrict__ wph)
{
    int idx = blockIdx.x * 256 + threadIdx.x;
    if (idx >= 16384) return;
    const float* src; unsigned short* dh; int off;
    if (idx < 12288) { src = wq; dh = wqh; off = idx; }
    else             { src = wp; dh = wph; off = idx - 12288; }
    float4 v = ((const float4*)src)[off];
    ushort4 h;
    h.x = f2h(v.x); h.y = f2h(v.y); h.z = f2h(v.z); h.w = f2h(v.w);
    ((ushort4*)dh)[off] = h;
}

// ---------------------------------------------------------------------------
// Fused-N MFMA GEMM, plain fp16 (1 MFMA/frag, mfma_f32_16x16x32_f16).
// grid = 392 m-blocks; A-tile staged once; NPH n-phases restage 16 KB B.
//  SELQKV=1: NPH=6, A = f32 x -> fp16 in-kernel; q/k/v scatter epilogue.
//  SELQKV=0: NPH=2, A = attn fp16; f32-row epilogue.
// LDS 32 KB.  XOR swizzle byte ^= (row&7)<<4 -> conflict-free b128 reads.
// ---------------------------------------------------------------------------
template <int SELQKV>
__global__ __launch_bounds__(256, 2) void gemm_fused(
    const float* __restrict__ Af32,
    const unsigned short* __restrict__ Axh,
    const unsigned short* __restrict__ Bgh,
    const float* __restrict__ bias,
    unsigned short* __restrict__ outq, unsigned short* __restrict__ outk,
    unsigned short* __restrict__ outv, float* __restrict__ outp)
{
    __shared__ unsigned short sAh[64 * 128];
    __shared__ unsigned short sBh[64 * 128];

    const int tid = threadIdx.x;
    const int m0 = blockIdx.x * 64;
    constexpr int NPH = SELQKV ? 6 : 2;

    // ---- stage A once (fp16) ----
    if constexpr (SELQKV) {
#pragma unroll
        for (int it = 0; it < 8; ++it) {
            int idx = tid + it * 256;          // 0..2047 float4 chunks
            int row = idx >> 5;                // 0..63
            int c4  = idx & 31;
            float4 a = *(const float4*)(Af32 + (size_t)(m0 + row) * 128 + c4 * 4);
            int byte = (row * 256 + c4 * 8) ^ ((row & 7) << 4);
            ushort4 h;
            h.x = f2h(a.x); h.y = f2h(a.y); h.z = f2h(a.z); h.w = f2h(a.w);
            *(ushort4*)((char*)sAh + byte) = h;
        }
    } else {
#pragma unroll
        for (int it = 0; it < 4; ++it) {
            int chunk = it * 256 + tid;        // 0..1023
            int row = chunk >> 4, c16 = chunk & 15;
            int byte = (row * 256 + c16 * 16) ^ ((row & 7) << 4);
            size_t ga = (size_t)(m0 + row) * 128 + c16 * 8;
            *(uint4*)((char*)sAh + byte) = *(const uint4*)(Axh + ga);
        }
    }

    const int lane = tid & 63;
    const int w  = tid >> 6;
    const int wr = w >> 1, wc = w & 1;       // 2x2 waves -> 64x64
    const int fr  = lane & 15;
    const int kqb = (lane >> 4) * 16;        // k byte offset within 64B group
    const int cl = lane & 15;
    const int rq = lane >> 4;

    for (int ph = 0; ph < NPH; ++ph) {
        const int n0 = ph * 64;
        if (ph > 0) __syncthreads();         // prior mfma reads done before B overwrite
#pragma unroll
        for (int it = 0; it < 4; ++it) {
            int chunk = it * 256 + tid;      // 0..1023
            int row = chunk >> 4, c16 = chunk & 15;
            int byte = (row * 256 + c16 * 16) ^ ((row & 7) << 4);
            size_t gb = (size_t)(n0 + row) * 128 + c16 * 8;
            *(uint4*)((char*)sBh + byte) = *(const uint4*)(Bgh + gb);
        }
        __syncthreads();

        f32x4 acc[2][2];
#pragma unroll
        for (int i = 0; i < 2; ++i)
#pragma unroll
            for (int j = 0; j < 2; ++j) acc[i][j] = (f32x4){0.f, 0.f, 0.f, 0.f};

#pragma unroll
        for (int ks = 0; ks < 4; ++ks) {
            short8v ah[2], bh[2];
#pragma unroll
            for (int mi = 0; mi < 2; ++mi) {
                int row = wr * 32 + mi * 16 + fr;
                int byte = (row * 256 + ks * 64 + kqb) ^ ((row & 7) << 4);
                ah[mi] = *(const short8v*)((const char*)sAh + byte);
            }
#pragma unroll
            for (int ni = 0; ni < 2; ++ni) {
                int row = wc * 32 + ni * 16 + fr;
                int byte = (row * 256 + ks * 64 + kqb) ^ ((row & 7) << 4);
                bh[ni] = *(const short8v*)((const char*)sBh + byte);
            }
#pragma unroll
            for (int mi = 0; mi < 2; ++mi)
#pragma unroll
                for (int ni = 0; ni < 2; ++ni)
                    acc[mi][ni] = __builtin_amdgcn_mfma_f32_16x16x32_f16(ah[mi], bh[ni], acc[mi][ni], 0, 0, 0);
        }

        // ---- epilogue: C/D layout col=lane&15, row=4*(lane>>4)+reg ----
#pragma unroll
        for (int mi = 0; mi < 2; ++mi) {
#pragma unroll
            for (int reg = 0; reg < 4; ++reg) {
                int m = m0 + wr * 32 + mi * 16 + rq * 4 + reg;
                if constexpr (SELQKV) {
                    int b = m / 3136;
                    int r = m - b * 3136;
                    int y = r / 56;
                    int x = r - y * 56;
#pragma unroll
                    for (int ni = 0; ni < 2; ++ni) {
                        int nn = n0 + wc * 32 + ni * 16 + cl;   // 0..383
                        float val = acc[mi][ni][reg] + bias[nn];
                        int sel = nn >> 7;                      // 0=q 1=k 2=v
                        int nl = nn & 127;
                        int h = nl >> 5, d = nl & 31;
                        size_t oi = ((size_t)((b * NH + h) * 3136) + y * 56 + x) * 32 + d;
                        if (sel == 0)      outq[oi] = f2h(val * SCALE);   // q fp16
                        else if (sel == 1) outk[oi] = f2h(val);
                        else               outv[oi] = f2h(val);
                    }
                } else {
#pragma unroll
                    for (int ni = 0; ni < 2; ++ni) {
                        int nn = n0 + wc * 32 + ni * 16 + cl;
                        outp[(size_t)m * 128 + nn] = acc[mi][ni][reg] + bias[nn];
                    }
                }
            }
        }
    }
}

// ---------------------------------------------------------------------------
// Neighborhood attention v8 (round-20 version — measured best, 52.2 us):
// 4 threads per (pixel,head) d-chunk split, 256 thr, 8x8 tile, halo 14x14,
// grid 49x4x8.  QK dot = packed fp16 (4 pk ops + f32 finish); q packed in
// 4 half2 regs.  V unpacked to f32 in LDS at staging (PV axpy = plain fmaf
// — round-21 showed fp16-V-in-LDS regresses: +4 cvt/key > occupancy gain).
// attn output fp16.  LDS 36.8 KB -> 4 blocks/CU = 16 waves/CU.
// ---------------------------------------------------------------------------
__global__ __launch_bounds__(256, 4) void natt_k(
    const unsigned short* __restrict__ qs, const unsigned short* __restrict__ kb,
    const unsigned short* __restrict__ vb, const float* __restrict__ rpb,
    unsigned short* __restrict__ attn_h)
{
    __shared__ uint4 ks[196 * 4];                    // K fp16 [pix][c], 12544 B
    __shared__ __align__(16) float vfs[4][1572];     // V f32 c-sections, 25152 B

    const int tid = threadIdx.x;
    const int b = blockIdx.z, h = blockIdx.y;
    const int tyy = blockIdx.x / 7, txx = blockIdx.x - tyy * 7;  // 7x7 tiles
    const int y0 = tyy * 8, x0 = txx * 8;
    const int bh = b * NH + h;

    const int p = tid >> 2, c = tid & 3;   // quads 4-aligned -> DPP partners co-active
    const int py = p >> 3;
    const int pxx = p & 7;

    // hoisted q load (fp16, 16B) — stays packed in 4 half2 regs
    __half2 q2[4];
    {
        uint4 qv = *(const uint4*)(qs +
            ((size_t)(bh * 3136) + (y0 + py) * 56 + (x0 + pxx)) * 32 + c * 8);
        q2[0] = *(__half2*)&qv.x; q2[1] = *(__half2*)&qv.y;
        q2[2] = *(__half2*)&qv.z; q2[3] = *(__half2*)&qv.w;
    }

    const uint4* kg = (const uint4*)kb;  // 4 uint4 per pixel (32 fp16)
    const uint4* vg = (const uint4*)vb;
    for (int idx = tid; idx < 784; idx += 256) {   // 196 pix * 4 chunks
        int pix = idx >> 2, cc = idx & 3;
        int i = pix / 14;
        int j = pix - i * 14;
        int y = y0 + i - PAD;
        int x = x0 + j - PAD;
        uint4 zk = make_uint4(0u, 0u, 0u, 0u);
        uint4 zv = make_uint4(0u, 0u, 0u, 0u);
        if ((unsigned)y < 56u && (unsigned)x < 56u) {
            int g = ((bh * 3136) + y * 56 + x) * 4 + cc;
            zk = kg[g];
            zv = vg[g];
        }
        ks[idx] = zk;
        float2 f0 = __half22float2(*(__half2*)&zv.x);
        float2 f1 = __half22float2(*(__half2*)&zv.y);
        float2 f2 = __half22float2(*(__half2*)&zv.z);
        float2 f3 = __half22float2(*(__half2*)&zv.w);
        float* vd = &vfs[cc][pix * 8];
        vd[0] = f0.x; vd[1] = f0.y; vd[2] = f1.x; vd[3] = f1.y;
        vd[4] = f2.x; vd[5] = f2.y; vd[6] = f3.x; vd[7] = f3.y;
    }
    __syncthreads();

    float acc[8];
#pragma unroll
    for (int d = 0; d < 8; ++d) acc[d] = 0.f;
    float l = 0.f;

    const float* rph = rpb + h * 49;       // uniform index -> scalar loads
    const float* vbase = &vfs[c][0];

#pragma unroll
    for (int dy = 0; dy < 7; ++dy) {
        int rowpix = (py + dy) * 14 + pxx;
#pragma unroll
        for (int dx = 0; dx < 7; ++dx) {
            int pix = rowpix + dx;
            float s  = dot8h(q2, ks[pix * 4 + c]);
            float sf = quad_sum(s) + rph[dy * 7 + dx];
            float e  = __expf(sf);
            l += e;
            const float* vv = vbase + pix * 8;
            float4 v0 = *(const float4*)(vv);
            float4 v1 = *(const float4*)(vv + 4);
            acc[0] = fmaf(e, v0.x, acc[0]); acc[1] = fmaf(e, v0.y, acc[1]);
            acc[2] = fmaf(e, v0.z, acc[2]); acc[3] = fmaf(e, v0.w, acc[3]);
            acc[4] = fmaf(e, v1.x, acc[4]); acc[5] = fmaf(e, v1.y, acc[5]);
            acc[6] = fmaf(e, v1.z, acc[6]); acc[7] = fmaf(e, v1.w, acc[7]);
        }
    }

    float rl = 1.0f / l;

    // pack 8 dims -> fp16 uint4, single b128 store
    unsigned short hv[8];
#pragma unroll
    for (int d = 0; d < 8; ++d) hv[d] = f2h(acc[d] * rl);
    uint4 uh;
    uh.x = (unsigned)hv[0] | ((unsigned)hv[1] << 16);
    uh.y = (unsigned)hv[2] | ((unsigned)hv[3] << 16);
    uh.z = (unsigned)hv[4] | ((unsigned)hv[5] << 16);
    uh.w = (unsigned)hv[6] | ((unsigned)hv[7] << 16);

    size_t base = ((size_t)(b * 3136) + (y0 + py) * 56 + (x0 + pxx)) * 128 + h * 32 + c * 8;
    *(uint4*)(attn_h + base) = uh;
}

extern "C" void kernel_launch(void* const* d_in, const int* in_sizes, int n_in,
                              void* d_out, int out_size, void* d_ws, size_t ws_size,
                              hipStream_t stream)
{
    const float* x     = (const float*)d_in[0];
    const float* Wqkv  = (const float*)d_in[1];
    const float* bqkv  = (const float*)d_in[2];
    const float* rpb   = (const float*)d_in[3];
    const float* Wproj = (const float*)d_in[4];
    const float* bproj = (const float*)d_in[5];
    float* out = (float*)d_out;

    char* ws = (char*)d_ws;
    unsigned short* qsb  = (unsigned short*)(ws + QS_OFF);   // q fp16 (pre-scaled)
    unsigned short* kbuf = (unsigned short*)(ws + K_OFF);
    unsigned short* vbuf = (unsigned short*)(ws + V_OFF);
    unsigned short* xh   = (unsigned short*)(ws + XH_OFF);   // attn fp16 (from natt)
    unsigned short* wqh  = (unsigned short*)(ws + WQH_OFF);
    unsigned short* wph  = (unsigned short*)(ws + WPH_OFF);

    // 0) convert weights to fp16 (tiny)
    split_k<<<64, 256, 0, stream>>>(Wqkv, Wproj, wqh, wph);

    // 1) QKV projection: 392 m-blocks, 6 internal n-phases (A staged once,
    //    plain fp16 -> 1 MFMA/frag, 32 KB LDS)
    gemm_fused<1><<<392, 256, 0, stream>>>(x, nullptr, wqh, bqkv,
                                           qsb, kbuf, vbuf, nullptr);

    // 2) neighborhood attention (v8, packed fp16 QK): 49 x 4 x 8, 256 thr
    natt_k<<<dim3(49, NH, 8), 256, 0, stream>>>(qsb, kbuf, vbuf, rpb, xh);

    // 3) output projection: 392 m-blocks, 2 internal n-phases, plain fp16
    gemm_fused<0><<<392, 256, 0, stream>>>(nullptr, xh, wph, bproj,
                                           nullptr, nullptr, nullptr, out);
}